// Round 5
// baseline (622.169 us; speedup 1.0000x reference)
//
#include <hip/hip_runtime.h>
#include <math.h>

#define B_ 512
#define T_ 128
#define D_ 512
#define O_ 10

typedef unsigned int uint32;
typedef short bf16x8 __attribute__((ext_vector_type(8)));   // 8 bf16 = 4 VGPRs
typedef float f32x4 __attribute__((ext_vector_type(4)));

__device__ __forceinline__ uint32 bf16rne(float f) {
    uint32 u = __float_as_uint(f);
    return (u + 0x7FFFu + ((u >> 16) & 1u)) >> 16;
}
__device__ __forceinline__ float bf16f(uint32 h) { return __uint_as_float(h << 16); }

// ---------------- pre-split W1 into 3 bf16 planes [3][512][512] ----------------
__global__ __launch_bounds__(256)
void presplitW_kernel(const float* __restrict__ W1, unsigned short* __restrict__ Wsp)
{
    const int idx = blockIdx.x * 256 + threadIdx.x;
    const float4 v = *(const float4*)(W1 + (size_t)idx * 4);
    float vv[4] = {v.x, v.y, v.z, v.w};
    uint32 c0[4], c1[4], c2[4];
#pragma unroll
    for (int i = 0; i < 4; ++i) {
        c0[i] = bf16rne(vv[i]);
        float r = vv[i] - bf16f(c0[i]);
        c1[i] = bf16rne(r);
        float r2 = r - bf16f(c1[i]);
        c2[i] = bf16rne(r2);
    }
    const size_t base = (size_t)idx * 4;
    uint2 w;
    w.x = c0[0] | (c0[1] << 16); w.y = c0[2] | (c0[3] << 16);
    *(uint2*)(Wsp + base) = w;
    w.x = c1[0] | (c1[1] << 16); w.y = c1[2] | (c1[3] << 16);
    *(uint2*)(Wsp + 262144 + base) = w;
    w.x = c2[0] | (c2[1] << 16); w.y = c2[2] | (c2[3] << 16);
    *(uint2*)(Wsp + 524288 + base) = w;
}

// ---------------- GEMM1: bf16x3-split MFMA + fused fp64 BN partials ----------------
// SPW=34: 68B row stride = 17 banks (odd) -> fragment reads conflict-free;
// LDS 52.2 KB -> 3 blocks/CU (was 61.4 KB / 2 blocks at SPW=40).
#define SPW 34
#define SPL (128*SPW)

__global__ __launch_bounds__(256)
void gemm1_kernel(const float* __restrict__ data, const float* __restrict__ drop,
                  const unsigned short* __restrict__ Wsp, const float* __restrict__ b1,
                  float* __restrict__ hbuf, double* __restrict__ pSum,
                  double* __restrict__ pSq, int t0, int Tc)
{
    __shared__ __align__(16) unsigned short As3[3 * SPL];
    __shared__ __align__(16) unsigned short Ws3[3 * SPL];

    const int tid = threadIdx.x;
    const int bid = blockIdx.x;
    // XCD swizzle (verified R3: FETCH 606->159MB)
    const int xcd = bid & 7;
    const int rest = bid >> 3;
    const int yy = rest & 3;
    const int g = (rest >> 2) * 8 + xcd;

    const int R = g * 128;
    const int tc = R >> 9;
    const int b_base = R & 511;
    const int t = t0 + tc;
    const int d0 = yy * 128;

    const int w = tid >> 6;
    const int lane = tid & 63;
    const int wm = w & 1, wn = w >> 1;
    const int q = lane >> 4, r16 = lane & 15;

    const int lm = tid >> 2;          // row within slab for A staging (i adds 64)
    const int kg = (tid & 3) * 8;     // k-subgroup

    f32x4 acc[4][4];
#pragma unroll
    for (int i = 0; i < 4; ++i)
#pragma unroll
        for (int j = 0; j < 4; ++j) acc[i][j] = (f32x4){0.f, 0.f, 0.f, 0.f};

    // A prefetch registers (data+mask for 2 row-halves x 8 k each)
    float4 pd[2][2], pm[2][2];

#define LOADA(K0)                                                                \
    {                                                                            \
        _Pragma("unroll")                                                        \
        for (int i = 0; i < 2; ++i) {                                            \
            const int m = lm + i * 64;                                           \
            const float* dsrc = data + ((size_t)(b_base + m) * T_ + t) * D_ + (K0) + kg; \
            const float* msrc = drop + ((size_t)t * B_ + b_base + m) * D_ + (K0) + kg;   \
            pd[i][0] = *(const float4*)(dsrc);                                   \
            pd[i][1] = *(const float4*)(dsrc + 4);                               \
            pm[i][0] = *(const float4*)(msrc);                                   \
            pm[i][1] = *(const float4*)(msrc + 4);                               \
        }                                                                        \
    }

    LOADA(0)   // prologue

    for (int k0 = 0; k0 < 512; k0 += 32) {
        // ---- W loads issue first (latency overlaps the A-split VALU below) ----
        uint4 pw[6];
#pragma unroll
        for (int i = 0; i < 6; ++i) {
            const int p = tid + i * 256;
            const int s = p >> 9;
            const int rem = p & 511;
            const int n = rem >> 2;
            const int kg2 = (rem & 3) * 8;
            pw[i] = *(const uint4*)(Wsp + (size_t)s * 262144
                                    + (size_t)(d0 + n) * 512 + k0 + kg2);
        }
        // ---- A: mask-mul + 3-way RNE split from prefetched regs -> LDS ----
#pragma unroll
        for (int i = 0; i < 2; ++i) {
            float vv[8] = {pd[i][0].x*pm[i][0].x, pd[i][0].y*pm[i][0].y,
                           pd[i][0].z*pm[i][0].z, pd[i][0].w*pm[i][0].w,
                           pd[i][1].x*pm[i][1].x, pd[i][1].y*pm[i][1].y,
                           pd[i][1].z*pm[i][1].z, pd[i][1].w*pm[i][1].w};
            uint32 u0[8], u1[8], u2[8];
#pragma unroll
            for (int e = 0; e < 8; ++e) {
                u0[e] = bf16rne(vv[e]);
                const float r = vv[e] - bf16f(u0[e]);
                u1[e] = bf16rne(r);
                const float r2 = r - bf16f(u1[e]);
                u2[e] = bf16rne(r2);
            }
            const int dst = (lm + i * 64) * SPW + kg;
            uint4 pk;
            pk.x = u0[0]|(u0[1]<<16); pk.y = u0[2]|(u0[3]<<16);
            pk.z = u0[4]|(u0[5]<<16); pk.w = u0[6]|(u0[7]<<16);
            *(uint4*)(&As3[dst]) = pk;
            pk.x = u1[0]|(u1[1]<<16); pk.y = u1[2]|(u1[3]<<16);
            pk.z = u1[4]|(u1[5]<<16); pk.w = u1[6]|(u1[7]<<16);
            *(uint4*)(&As3[SPL + dst]) = pk;
            pk.x = u2[0]|(u2[1]<<16); pk.y = u2[2]|(u2[3]<<16);
            pk.z = u2[4]|(u2[5]<<16); pk.w = u2[6]|(u2[7]<<16);
            *(uint4*)(&As3[2*SPL + dst]) = pk;
        }
        // ---- W regs -> LDS ----
#pragma unroll
        for (int i = 0; i < 6; ++i) {
            const int p = tid + i * 256;
            const int s = p >> 9;
            const int rem = p & 511;
            const int n = rem >> 2;
            const int kg2 = (rem & 3) * 8;
            *(uint4*)(&Ws3[s * SPL + n * SPW + kg2]) = pw[i];
        }
        __syncthreads();

        bf16x8 af[4][3], bfr[4][3];
#pragma unroll
        for (int mt = 0; mt < 4; ++mt)
#pragma unroll
            for (int s = 0; s < 3; ++s)
                af[mt][s] = *(const bf16x8*)(&As3[s*SPL + (wm*64 + mt*16 + r16)*SPW + q*8]);
#pragma unroll
        for (int nt = 0; nt < 4; ++nt)
#pragma unroll
            for (int s = 0; s < 3; ++s)
                bfr[nt][s] = *(const bf16x8*)(&Ws3[s*SPL + (wn*64 + nt*16 + r16)*SPW + q*8]);

        // ---- prefetch next A while MFMAs run ----
        if (k0 + 32 < 512) LOADA(k0 + 32)

#define PRODUCT(SA, SB)                                                          \
        {                                                                        \
            _Pragma("unroll")                                                    \
            for (int mt = 0; mt < 4; ++mt) {                                     \
                _Pragma("unroll")                                                \
                for (int nt = 0; nt < 4; ++nt)                                   \
                    acc[mt][nt] = __builtin_amdgcn_mfma_f32_16x16x32_bf16(       \
                        af[mt][SA], bfr[nt][SB], acc[mt][nt], 0, 0, 0);          \
            }                                                                    \
        }
        PRODUCT(0, 0)
        PRODUCT(0, 1)
        PRODUCT(1, 0)
        PRODUCT(1, 1)
        PRODUCT(0, 2)
        PRODUCT(2, 0)
#undef PRODUCT
        __syncthreads();
    }

    // ---- epilogue: +b1, write hbuf, fp64 per-block BN partials (bitwise = R4) ----
    float b1c[4];
#pragma unroll
    for (int nt = 0; nt < 4; ++nt) b1c[nt] = b1[d0 + wn*64 + nt*16 + r16];

    double sd[4], sq[4];
#pragma unroll
    for (int nt = 0; nt < 4; ++nt) { sd[nt] = 0.0; sq[nt] = 0.0; }

#pragma unroll
    for (int mt = 0; mt < 4; ++mt)
#pragma unroll
        for (int r = 0; r < 4; ++r) {
            const int row = R + wm*64 + mt*16 + q*4 + r;
            float* op = hbuf + (size_t)row * D_ + d0 + wn*64 + r16;
#pragma unroll
            for (int nt = 0; nt < 4; ++nt) {
                const float hf = acc[mt][nt][r] + b1c[nt];
                op[nt*16] = hf;
                const double dh = (double)hf;
                sd[nt] += dh;
                sq[nt] = fma(dh, dh, sq[nt]);
            }
        }
#pragma unroll
    for (int nt = 0; nt < 4; ++nt) {
        sd[nt] += __shfl_xor(sd[nt], 16); sd[nt] += __shfl_xor(sd[nt], 32);
        sq[nt] += __shfl_xor(sq[nt], 16); sq[nt] += __shfl_xor(sq[nt], 32);
    }
    double* dsh = (double*)&As3[0];
    __syncthreads();
    if (q == 0) {
#pragma unroll
        for (int nt = 0; nt < 4; ++nt) {
            dsh[(w*64 + nt*16 + r16)*2 + 0] = sd[nt];
            dsh[(w*64 + nt*16 + r16)*2 + 1] = sq[nt];
        }
    }
    __syncthreads();
    if (tid < 128) {
        const int col = tid;
        const int gg = col >> 6, c = col & 63;
        const double S = dsh[((2*gg)*64 + c)*2 + 0] + dsh[((2*gg+1)*64 + c)*2 + 0];
        const double Q = dsh[((2*gg)*64 + c)*2 + 1] + dsh[((2*gg+1)*64 + c)*2 + 1];
        const int bt = b_base >> 7;
        pSum[((size_t)(bt*Tc + tc))*D_ + d0 + col] = S;
        pSq [((size_t)(bt*Tc + tc))*D_ + d0 + col] = Q;
    }
}

// ---------------- finalize ----------------
__global__ __launch_bounds__(256)
void finalize_kernel(const double* __restrict__ pSum, const double* __restrict__ pSq,
                     const float* __restrict__ gamma, const float* __restrict__ bn_beta,
                     float* __restrict__ scaleArr, float* __restrict__ shiftArr, int Tc)
{
    const int tc = blockIdx.x;
    const int d = blockIdx.y * 256 + threadIdx.x;
    double S = 0.0, Q = 0.0;
#pragma unroll
    for (int bt = 0; bt < 4; ++bt) {
        S += pSum[((size_t)(bt * Tc + tc)) * D_ + d];
        Q += pSq [((size_t)(bt * Tc + tc)) * D_ + d];
    }
    const double mean = S / (double)B_;
    const double var  = Q / (double)B_ - mean * mean;
    const double rs   = 1.0 / sqrt(var + 1e-5);
    const double gm   = (double)gamma[d] * rs;
    scaleArr[tc * D_ + d] = (float)gm;
    shiftArr[tc * D_ + d] = (float)((double)bn_beta[d] - gm * mean);
}

// ---------------- scanA: 1 element/thread (262144 threads = 16 waves/CU) ----------------
__global__ __launch_bounds__(256)
void scanA_kernel(const float* __restrict__ hbuf, const float* __restrict__ scaleArr,
                  const float* __restrict__ shiftArr, unsigned short* __restrict__ spk,
                  float* __restrict__ sMem1, float* __restrict__ sSpk1, int t0, int Tc)
{
    const int e = blockIdx.x * 256 + threadIdx.x;   // b*512 + d
    const int b = e >> 9;
    const int d = e & 511;

    float m1, s1;
    if (t0 == 0) { m1 = 0.f; s1 = 0.f; }
    else { m1 = sMem1[e]; s1 = sSpk1[e]; }

    float hv = hbuf[e];
    float sc = scaleArr[d];
    float sf = shiftArr[d];

    for (int tc = 0; tc < Tc; ++tc) {
        float hvN, scN, sfN;
        if (tc + 1 < Tc) {
            hvN = hbuf[(size_t)(tc + 1) * (B_ * D_) + e];
            scN = scaleArr[(tc + 1) * D_ + d];
            sfN = shiftArr[(tc + 1) * D_ + d];
        }
        const float cur1 = fmaf(sc, hv, sf);
        m1 = fmaf(0.5f, m1, cur1) - s1;
        s1 = ((m1 - 1.0f) > 0.f) ? 1.f : 0.f;
        spk[(size_t)tc * (B_ * D_) + e] = (s1 == 1.f) ? (unsigned short)0x3F80u
                                                      : (unsigned short)0u;
        hv = hvN; sc = scN; sf = sfN;
    }

    sMem1[e] = m1;
    sSpk1[e] = s1;
}

// ---------------- gemm2: wave per 4 rows ----------------
__global__ __launch_bounds__(256)
void gemm2_kernel(const unsigned short* __restrict__ spk, const float* __restrict__ W2,
                  const float* __restrict__ b2, float* __restrict__ cur2)
{
    const int tid = threadIdx.x;
    const int w = tid >> 6, lane = tid & 63;
    const int rowBase = blockIdx.x * 16 + w * 4;

    float w2r[O_][8];
#pragma unroll
    for (int o = 0; o < O_; ++o) {
        const float4 wa = *(const float4*)(W2 + o * D_ + lane * 8);
        const float4 wb = *(const float4*)(W2 + o * D_ + lane * 8 + 4);
        w2r[o][0] = wa.x; w2r[o][1] = wa.y; w2r[o][2] = wa.z; w2r[o][3] = wa.w;
        w2r[o][4] = wb.x; w2r[o][5] = wb.y; w2r[o][6] = wb.z; w2r[o][7] = wb.w;
    }
    float b2v[O_];
#pragma unroll
    for (int o = 0; o < O_; ++o) b2v[o] = b2[o];

    for (int rr = 0; rr < 4; ++rr) {
        const int row = rowBase + rr;
        const uint4 sv = *(const uint4*)(spk + (size_t)row * D_ + lane * 8);
        float f[8];
        f[0] = bf16f(sv.x & 0xFFFFu); f[1] = bf16f(sv.x >> 16);
        f[2] = bf16f(sv.y & 0xFFFFu); f[3] = bf16f(sv.y >> 16);
        f[4] = bf16f(sv.z & 0xFFFFu); f[5] = bf16f(sv.z >> 16);
        f[6] = bf16f(sv.w & 0xFFFFu); f[7] = bf16f(sv.w >> 16);
        float p[O_];
#pragma unroll
        for (int o = 0; o < O_; ++o) {
            float v = f[0] * w2r[o][0];
#pragma unroll
            for (int j = 1; j < 8; ++j) v = fmaf(f[j], w2r[o][j], v);
            p[o] = v;
        }
#pragma unroll
        for (int o = 0; o < O_; ++o) {
#pragma unroll
            for (int off = 32; off > 0; off >>= 1)
                p[o] += __shfl_xor(p[o], off);
        }
        float outv = 0.f;
#pragma unroll
        for (int o = 0; o < O_; ++o)
            if (lane == o) outv = p[o] + b2v[o];
        if (lane < O_)
            cur2[(size_t)row * O_ + lane] = outv;
    }
}

// ---------------- scanB ----------------
__global__ __launch_bounds__(256)
void scanB_kernel(const float* __restrict__ cur2, float* __restrict__ out,
                  float* __restrict__ sMem2, float* __restrict__ sSpk2, int t0, int Tc)
{
    const int idx = blockIdx.x * 256 + threadIdx.x;
    float mem2, spk2;
    if (t0 == 0) { mem2 = 0.f; spk2 = 0.f; }
    else { mem2 = sMem2[idx]; spk2 = sSpk2[idx]; }

    float v[4], vn[4];
#pragma unroll
    for (int j = 0; j < 4; ++j) v[j] = cur2[(size_t)j * (B_ * O_) + idx];

    for (int tg = 0; tg < Tc; tg += 4) {
        if (tg + 4 < Tc) {
#pragma unroll
            for (int j = 0; j < 4; ++j)
                vn[j] = cur2[(size_t)(tg + 4 + j) * (B_ * O_) + idx];
        }
#pragma unroll
        for (int j = 0; j < 4; ++j) {
            mem2 = fmaf(0.5f, mem2, v[j]) - spk2;
            spk2 = ((mem2 - 1.0f) > 0.f) ? 1.f : 0.f;
            out[(size_t)(t0 + tg + j) * (B_ * O_) + idx] = spk2;
        }
#pragma unroll
        for (int j = 0; j < 4; ++j) v[j] = vn[j];
    }
    sMem2[idx] = mem2;
    sSpk2[idx] = spk2;
}

extern "C" void kernel_launch(void* const* d_in, const int* in_sizes, int n_in,
                              void* d_out, int out_size, void* d_ws, size_t ws_size,
                              hipStream_t stream) {
    const float* data    = (const float*)d_in[0];
    const float* drop    = (const float*)d_in[1];
    const float* W1      = (const float*)d_in[2];
    const float* b1      = (const float*)d_in[3];
    const float* gamma   = (const float*)d_in[4];
    const float* bn_beta = (const float*)d_in[5];
    const float* W2      = (const float*)d_in[6];
    const float* b2      = (const float*)d_in[7];
    float* out = (float*)d_out;

    const size_t fixedBytes = 1572864 + 2*1048576 + 2*20480;
    const size_t perT = 1048576 + 524288 + 20480 + 4096 + 32768;
    int Tc = T_;
    while (Tc > 2 && fixedBytes + (size_t)Tc * perT > ws_size) Tc >>= 1;

    char* p = (char*)d_ws;
    double* pSum    = (double*)p; p += (size_t)4 * Tc * D_ * 8;
    double* pSq     = (double*)p; p += (size_t)4 * Tc * D_ * 8;
    float* hbuf     = (float*)p; p += (size_t)Tc * B_ * D_ * 4;
    float* scaleArr = (float*)p; p += (size_t)Tc * D_ * 4;
    float* shiftArr = (float*)p; p += (size_t)Tc * D_ * 4;
    float* sMem1    = (float*)p; p += (size_t)B_ * D_ * 4;
    float* sSpk1    = (float*)p; p += (size_t)B_ * D_ * 4;
    float* sMem2    = (float*)p; p += (size_t)B_ * O_ * 4;
    float* sSpk2    = (float*)p; p += (size_t)B_ * O_ * 4;
    float* cur2     = (float*)p; p += (size_t)Tc * B_ * O_ * 4;
    unsigned short* Wsp = (unsigned short*)p; p += (size_t)3 * D_ * D_ * 2;
    unsigned short* spk = (unsigned short*)p; p += (size_t)Tc * B_ * D_ * 2;

    presplitW_kernel<<<256, 256, 0, stream>>>(W1, Wsp);

    for (int t0 = 0; t0 < T_; t0 += Tc) {
        gemm1_kernel<<<Tc * 16, 256, 0, stream>>>(data, drop, Wsp, b1, hbuf,
                                                  pSum, pSq, t0, Tc);
        finalize_kernel<<<dim3(Tc, D_ / 256), 256, 0, stream>>>(
            pSum, pSq, gamma, bn_beta, scaleArr, shiftArr, Tc);
        scanA_kernel<<<(B_ * D_) / 256, 256, 0, stream>>>(hbuf, scaleArr, shiftArr, spk,
                                                          sMem1, sSpk1, t0, Tc);
        gemm2_kernel<<<Tc * 32, 256, 0, stream>>>(spk, W2, b2, cur2);
        scanB_kernel<<<20, 256, 0, stream>>>(cur2, out, sMem2, sSpk2, t0, Tc);
    }
}

// Round 6
// 540.980 us; speedup vs baseline: 1.1501x; 1.1501x over previous
//
#include <hip/hip_runtime.h>
#include <math.h>

#define B_ 512
#define T_ 128
#define D_ 512
#define O_ 10

typedef unsigned int uint32;
typedef unsigned long long uint64;
typedef short bf16x8 __attribute__((ext_vector_type(8)));   // 8 bf16 = 4 VGPRs
typedef float f32x4 __attribute__((ext_vector_type(4)));

__device__ __forceinline__ uint32 bf16rne(float f) {
    uint32 u = __float_as_uint(f);
    return (u + 0x7FFFu + ((u >> 16) & 1u)) >> 16;
}
__device__ __forceinline__ float bf16f(uint32 h) { return __uint_as_float(h << 16); }

// ---------------- pre-split W1 into 3 bf16 planes [3][512][512] ----------------
__global__ __launch_bounds__(256)
void presplitW_kernel(const float* __restrict__ W1, unsigned short* __restrict__ Wsp)
{
    const int idx = blockIdx.x * 256 + threadIdx.x;
    const float4 v = *(const float4*)(W1 + (size_t)idx * 4);
    float vv[4] = {v.x, v.y, v.z, v.w};
    uint32 c0[4], c1[4], c2[4];
#pragma unroll
    for (int i = 0; i < 4; ++i) {
        c0[i] = bf16rne(vv[i]);
        float r = vv[i] - bf16f(c0[i]);
        c1[i] = bf16rne(r);
        float r2 = r - bf16f(c1[i]);
        c2[i] = bf16rne(r2);
    }
    const size_t base = (size_t)idx * 4;
    uint2 w;
    w.x = c0[0] | (c0[1] << 16); w.y = c0[2] | (c0[3] << 16);
    *(uint2*)(Wsp + base) = w;
    w.x = c1[0] | (c1[1] << 16); w.y = c1[2] | (c1[3] << 16);
    *(uint2*)(Wsp + 262144 + base) = w;
    w.x = c2[0] | (c2[1] << 16); w.y = c2[2] | (c2[3] << 16);
    *(uint2*)(Wsp + 524288 + base) = w;
}

// ---------------- GEMM1: bf16x3-split MFMA + fused fp64 BN partials ----------------
// EXACT R4 structure (253 us verified). SPW=40: 80B row stride = 5x16B, every row
// 16B-aligned for b128 (SPW=34's 68B stride broke alignment -> R5 regression).
#define SPW 40
#define SPL (128*SPW)

__global__ __launch_bounds__(256)
void gemm1_kernel(const float* __restrict__ data, const float* __restrict__ drop,
                  const unsigned short* __restrict__ Wsp, const float* __restrict__ b1,
                  float* __restrict__ hbuf, double* __restrict__ pSum,
                  double* __restrict__ pSq, int t0, int Tc)
{
    __shared__ __align__(16) unsigned short As3[3 * SPL];
    __shared__ __align__(16) unsigned short Ws3[3 * SPL];

    const int tid = threadIdx.x;
    const int bid = blockIdx.x;
    // XCD swizzle (verified R3: FETCH 606->159MB)
    const int xcd = bid & 7;
    const int rest = bid >> 3;
    const int yy = rest & 3;
    const int g = (rest >> 2) * 8 + xcd;

    const int R = g * 128;
    const int tc = R >> 9;
    const int b_base = R & 511;
    const int t = t0 + tc;
    const int d0 = yy * 128;

    const int w = tid >> 6;
    const int lane = tid & 63;
    const int wm = w & 1, wn = w >> 1;
    const int q = lane >> 4, r16 = lane & 15;

    f32x4 acc[4][4];
#pragma unroll
    for (int i = 0; i < 4; ++i)
#pragma unroll
        for (int j = 0; j < 4; ++j) acc[i][j] = (f32x4){0.f, 0.f, 0.f, 0.f};

    for (int k0 = 0; k0 < 512; k0 += 32) {
        // ---- stage A: load fp32, mask-mul, 3-way bf16 split, write 3 LDS planes ----
#pragma unroll
        for (int i = 0; i < 2; ++i) {
            const int p = tid + i * 256;
            const int m = p >> 2;
            const int kg = (p & 3) * 8;
            const float* dsrc = data + ((size_t)(b_base + m) * T_ + t) * D_ + k0 + kg;
            const float* msrc = drop + ((size_t)t * B_ + b_base + m) * D_ + k0 + kg;
            const float4 dv0 = *(const float4*)(dsrc);
            const float4 dv1 = *(const float4*)(dsrc + 4);
            const float4 mv0 = *(const float4*)(msrc);
            const float4 mv1 = *(const float4*)(msrc + 4);
            float vv[8] = {dv0.x*mv0.x, dv0.y*mv0.y, dv0.z*mv0.z, dv0.w*mv0.w,
                           dv1.x*mv1.x, dv1.y*mv1.y, dv1.z*mv1.z, dv1.w*mv1.w};
            uint32 u0[8], u1[8], u2[8];
#pragma unroll
            for (int e = 0; e < 8; ++e) {
                u0[e] = bf16rne(vv[e]);
                const float r = vv[e] - bf16f(u0[e]);
                u1[e] = bf16rne(r);
                const float r2 = r - bf16f(u1[e]);
                u2[e] = bf16rne(r2);
            }
            const int dst = m * SPW + kg;
            uint4 pk;
            pk.x = u0[0]|(u0[1]<<16); pk.y = u0[2]|(u0[3]<<16);
            pk.z = u0[4]|(u0[5]<<16); pk.w = u0[6]|(u0[7]<<16);
            *(uint4*)(&As3[dst]) = pk;
            pk.x = u1[0]|(u1[1]<<16); pk.y = u1[2]|(u1[3]<<16);
            pk.z = u1[4]|(u1[5]<<16); pk.w = u1[6]|(u1[7]<<16);
            *(uint4*)(&As3[SPL + dst]) = pk;
            pk.x = u2[0]|(u2[1]<<16); pk.y = u2[2]|(u2[3]<<16);
            pk.z = u2[4]|(u2[5]<<16); pk.w = u2[6]|(u2[7]<<16);
            *(uint4*)(&As3[2*SPL + dst]) = pk;
        }
        // ---- stage B: copy pre-split W1 planes ----
#pragma unroll
        for (int i = 0; i < 6; ++i) {
            const int p = tid + i * 256;
            const int s = p >> 9;
            const int rem = p & 511;
            const int n = rem >> 2;
            const int kg = (rem & 3) * 8;
            const uint4 pk = *(const uint4*)(Wsp + (size_t)s * 262144
                                             + (size_t)(d0 + n) * 512 + k0 + kg);
            *(uint4*)(&Ws3[s * SPL + n * SPW + kg]) = pk;
        }
        __syncthreads();

        bf16x8 af[4][3], bfr[4][3];
#pragma unroll
        for (int mt = 0; mt < 4; ++mt)
#pragma unroll
            for (int s = 0; s < 3; ++s)
                af[mt][s] = *(const bf16x8*)(&As3[s*SPL + (wm*64 + mt*16 + r16)*SPW + q*8]);
#pragma unroll
        for (int nt = 0; nt < 4; ++nt)
#pragma unroll
            for (int s = 0; s < 3; ++s)
                bfr[nt][s] = *(const bf16x8*)(&Ws3[s*SPL + (wn*64 + nt*16 + r16)*SPW + q*8]);

#define PRODUCT(SA, SB)                                                          \
        {                                                                        \
            _Pragma("unroll")                                                    \
            for (int mt = 0; mt < 4; ++mt) {                                     \
                _Pragma("unroll")                                                \
                for (int nt = 0; nt < 4; ++nt)                                   \
                    acc[mt][nt] = __builtin_amdgcn_mfma_f32_16x16x32_bf16(       \
                        af[mt][SA], bfr[nt][SB], acc[mt][nt], 0, 0, 0);          \
            }                                                                    \
        }
        PRODUCT(0, 0)
        PRODUCT(0, 1)
        PRODUCT(1, 0)
        PRODUCT(1, 1)
        PRODUCT(0, 2)
        PRODUCT(2, 0)
#undef PRODUCT
        __syncthreads();
    }

    // ---- epilogue: +b1, write hbuf, fp64 per-block BN partials ----
    float b1c[4];
#pragma unroll
    for (int nt = 0; nt < 4; ++nt) b1c[nt] = b1[d0 + wn*64 + nt*16 + r16];

    double sd[4], sq[4];
#pragma unroll
    for (int nt = 0; nt < 4; ++nt) { sd[nt] = 0.0; sq[nt] = 0.0; }

#pragma unroll
    for (int mt = 0; mt < 4; ++mt)
#pragma unroll
        for (int r = 0; r < 4; ++r) {
            const int row = R + wm*64 + mt*16 + q*4 + r;
            float* op = hbuf + (size_t)row * D_ + d0 + wn*64 + r16;
#pragma unroll
            for (int nt = 0; nt < 4; ++nt) {
                const float hf = acc[mt][nt][r] + b1c[nt];
                op[nt*16] = hf;
                const double dh = (double)hf;
                sd[nt] += dh;
                sq[nt] = fma(dh, dh, sq[nt]);
            }
        }
#pragma unroll
    for (int nt = 0; nt < 4; ++nt) {
        sd[nt] += __shfl_xor(sd[nt], 16); sd[nt] += __shfl_xor(sd[nt], 32);
        sq[nt] += __shfl_xor(sq[nt], 16); sq[nt] += __shfl_xor(sq[nt], 32);
    }
    double* dsh = (double*)&As3[0];
    __syncthreads();
    if (q == 0) {
#pragma unroll
        for (int nt = 0; nt < 4; ++nt) {
            dsh[(w*64 + nt*16 + r16)*2 + 0] = sd[nt];
            dsh[(w*64 + nt*16 + r16)*2 + 1] = sq[nt];
        }
    }
    __syncthreads();
    if (tid < 128) {
        const int col = tid;
        const int gg = col >> 6, c = col & 63;
        const double S = dsh[((2*gg)*64 + c)*2 + 0] + dsh[((2*gg+1)*64 + c)*2 + 0];
        const double Q = dsh[((2*gg)*64 + c)*2 + 1] + dsh[((2*gg+1)*64 + c)*2 + 1];
        const int bt = b_base >> 7;
        pSum[((size_t)(bt*Tc + tc))*D_ + d0 + col] = S;
        pSq [((size_t)(bt*Tc + tc))*D_ + d0 + col] = Q;
    }
}

// ---------------- finalize ----------------
__global__ __launch_bounds__(256)
void finalize_kernel(const double* __restrict__ pSum, const double* __restrict__ pSq,
                     const float* __restrict__ gamma, const float* __restrict__ bn_beta,
                     float* __restrict__ scaleArr, float* __restrict__ shiftArr, int Tc)
{
    const int tc = blockIdx.x;
    const int d = blockIdx.y * 256 + threadIdx.x;
    double S = 0.0, Q = 0.0;
#pragma unroll
    for (int bt = 0; bt < 4; ++bt) {
        S += pSum[((size_t)(bt * Tc + tc)) * D_ + d];
        Q += pSq [((size_t)(bt * Tc + tc)) * D_ + d];
    }
    const double mean = S / (double)B_;
    const double var  = Q / (double)B_ - mean * mean;
    const double rs   = 1.0 / sqrt(var + 1e-5);
    const double gm   = (double)gamma[d] * rs;
    scaleArr[tc * D_ + d] = (float)gm;
    shiftArr[tc * D_ + d] = (float)((double)bn_beta[d] - gm * mean);
}

// ---------------- scanA: 1 element/thread; spikes -> 64-bit ballot mask ----------------
// Each wave = one b, 64 consecutive d (blocks of 256 never straddle a b boundary).
__global__ __launch_bounds__(256)
void scanA_kernel(const float* __restrict__ hbuf, const float* __restrict__ scaleArr,
                  const float* __restrict__ shiftArr, uint64* __restrict__ spkM,
                  float* __restrict__ sMem1, float* __restrict__ sSpk1, int t0, int Tc)
{
    const int e = blockIdx.x * 256 + threadIdx.x;   // b*512 + d
    const int b = e >> 9;
    const int d = e & 511;
    const int lane = threadIdx.x & 63;
    const int mword = (e >> 6);                     // global 64-d group = b*8 + (d>>6)

    float m1, s1;
    if (t0 == 0) { m1 = 0.f; s1 = 0.f; }
    else { m1 = sMem1[e]; s1 = sSpk1[e]; }

    float hv = hbuf[e];
    float sc = scaleArr[d];
    float sf = shiftArr[d];

    for (int tc = 0; tc < Tc; ++tc) {
        float hvN, scN, sfN;
        if (tc + 1 < Tc) {
            hvN = hbuf[(size_t)(tc + 1) * (B_ * D_) + e];
            scN = scaleArr[(tc + 1) * D_ + d];
            sfN = shiftArr[(tc + 1) * D_ + d];
        }
        const float cur1 = fmaf(sc, hv, sf);
        m1 = fmaf(0.5f, m1, cur1) - s1;
        s1 = ((m1 - 1.0f) > 0.f) ? 1.f : 0.f;

        const uint64 mask = __ballot(s1 == 1.f);
        if (lane == 0)
            spkM[(size_t)tc * (B_ * 8) + mword] = mask;

        hv = hvN; sc = scN; sf = sfN;
    }

    sMem1[e] = m1;
    sSpk1[e] = s1;
}

// ---------------- gemm2: spike-mask dot W2, wave per 4 rows ----------------
// f[j] reconstructed as exactly 1.0f/0.0f; fmaf chain textually identical to R4.
__global__ __launch_bounds__(256)
void gemm2_kernel(const uint64* __restrict__ spkM, const float* __restrict__ W2,
                  const float* __restrict__ b2, float* __restrict__ cur2)
{
    const int tid = threadIdx.x;
    const int w = tid >> 6, lane = tid & 63;
    const int rowBase = blockIdx.x * 16 + w * 4;

    float w2r[O_][8];
#pragma unroll
    for (int o = 0; o < O_; ++o) {
        const float4 wa = *(const float4*)(W2 + o * D_ + lane * 8);
        const float4 wb = *(const float4*)(W2 + o * D_ + lane * 8 + 4);
        w2r[o][0] = wa.x; w2r[o][1] = wa.y; w2r[o][2] = wa.z; w2r[o][3] = wa.w;
        w2r[o][4] = wb.x; w2r[o][5] = wb.y; w2r[o][6] = wb.z; w2r[o][7] = wb.w;
    }
    float b2v[O_];
#pragma unroll
    for (int o = 0; o < O_; ++o) b2v[o] = b2[o];

    for (int rr = 0; rr < 4; ++rr) {
        const int row = rowBase + rr;                      // t*B + b
        const uint64 mk = spkM[(size_t)row * 8 + (lane >> 3)];
        const uint32 byte = (uint32)(mk >> ((lane & 7) * 8)) & 0xFFu;
        float f[8];
#pragma unroll
        for (int j = 0; j < 8; ++j)
            f[j] = (byte & (1u << j)) ? 1.0f : 0.0f;
        float p[O_];
#pragma unroll
        for (int o = 0; o < O_; ++o) {
            float v = f[0] * w2r[o][0];
#pragma unroll
            for (int j = 1; j < 8; ++j) v = fmaf(f[j], w2r[o][j], v);
            p[o] = v;
        }
#pragma unroll
        for (int o = 0; o < O_; ++o) {
#pragma unroll
            for (int off = 32; off > 0; off >>= 1)
                p[o] += __shfl_xor(p[o], off);
        }
        float outv = 0.f;
#pragma unroll
        for (int o = 0; o < O_; ++o)
            if (lane == o) outv = p[o] + b2v[o];
        if (lane < O_)
            cur2[(size_t)row * O_ + lane] = outv;
    }
}

// ---------------- scanB ----------------
__global__ __launch_bounds__(256)
void scanB_kernel(const float* __restrict__ cur2, float* __restrict__ out,
                  float* __restrict__ sMem2, float* __restrict__ sSpk2, int t0, int Tc)
{
    const int idx = blockIdx.x * 256 + threadIdx.x;
    float mem2, spk2;
    if (t0 == 0) { mem2 = 0.f; spk2 = 0.f; }
    else { mem2 = sMem2[idx]; spk2 = sSpk2[idx]; }

    float v[4], vn[4];
#pragma unroll
    for (int j = 0; j < 4; ++j) v[j] = cur2[(size_t)j * (B_ * O_) + idx];

    for (int tg = 0; tg < Tc; tg += 4) {
        if (tg + 4 < Tc) {
#pragma unroll
            for (int j = 0; j < 4; ++j)
                vn[j] = cur2[(size_t)(tg + 4 + j) * (B_ * O_) + idx];
        }
#pragma unroll
        for (int j = 0; j < 4; ++j) {
            mem2 = fmaf(0.5f, mem2, v[j]) - spk2;
            spk2 = ((mem2 - 1.0f) > 0.f) ? 1.f : 0.f;
            out[(size_t)(t0 + tg + j) * (B_ * O_) + idx] = spk2;
        }
#pragma unroll
        for (int j = 0; j < 4; ++j) v[j] = vn[j];
    }
    sMem2[idx] = mem2;
    sSpk2[idx] = spk2;
}

extern "C" void kernel_launch(void* const* d_in, const int* in_sizes, int n_in,
                              void* d_out, int out_size, void* d_ws, size_t ws_size,
                              hipStream_t stream) {
    const float* data    = (const float*)d_in[0];
    const float* drop    = (const float*)d_in[1];
    const float* W1      = (const float*)d_in[2];
    const float* b1      = (const float*)d_in[3];
    const float* gamma   = (const float*)d_in[4];
    const float* bn_beta = (const float*)d_in[5];
    const float* W2      = (const float*)d_in[6];
    const float* b2      = (const float*)d_in[7];
    float* out = (float*)d_out;

    const size_t fixedBytes = 1572864 + 2*1048576 + 2*20480;
    // per-t: hbuf 1MB + spkM 32KB + cur2 20KB + scale/shift 4KB + pSum/pSq 32KB
    const size_t perT = 1048576 + 32768 + 20480 + 4096 + 32768;
    int Tc = T_;
    while (Tc > 2 && fixedBytes + (size_t)Tc * perT > ws_size) Tc >>= 1;

    char* p = (char*)d_ws;
    double* pSum    = (double*)p; p += (size_t)4 * Tc * D_ * 8;
    double* pSq     = (double*)p; p += (size_t)4 * Tc * D_ * 8;
    float* hbuf     = (float*)p; p += (size_t)Tc * B_ * D_ * 4;
    float* scaleArr = (float*)p; p += (size_t)Tc * D_ * 4;
    float* shiftArr = (float*)p; p += (size_t)Tc * D_ * 4;
    float* sMem1    = (float*)p; p += (size_t)B_ * D_ * 4;
    float* sSpk1    = (float*)p; p += (size_t)B_ * D_ * 4;
    float* sMem2    = (float*)p; p += (size_t)B_ * O_ * 4;
    float* sSpk2    = (float*)p; p += (size_t)B_ * O_ * 4;
    float* cur2     = (float*)p; p += (size_t)Tc * B_ * O_ * 4;
    unsigned short* Wsp = (unsigned short*)p; p += (size_t)3 * D_ * D_ * 2;
    uint64* spkM    = (uint64*)p; p += (size_t)Tc * B_ * 8 * 8;

    presplitW_kernel<<<256, 256, 0, stream>>>(W1, Wsp);

    for (int t0 = 0; t0 < T_; t0 += Tc) {
        gemm1_kernel<<<Tc * 16, 256, 0, stream>>>(data, drop, Wsp, b1, hbuf,
                                                  pSum, pSq, t0, Tc);
        finalize_kernel<<<dim3(Tc, D_ / 256), 256, 0, stream>>>(
            pSum, pSq, gamma, bn_beta, scaleArr, shiftArr, Tc);
        scanA_kernel<<<(B_ * D_) / 256, 256, 0, stream>>>(hbuf, scaleArr, shiftArr, spkM,
                                                          sMem1, sSpk1, t0, Tc);
        gemm2_kernel<<<Tc * 32, 256, 0, stream>>>(spkM, W2, b2, cur2);
        scanB_kernel<<<20, 256, 0, stream>>>(cur2, out, sMem2, sSpk2, t0, Tc);
    }
}